// Round 1
// baseline (437.734 us; speedup 1.0000x reference)
//
#include <hip/hip_runtime.h>

#define N_NODES 20000
#define N_EDGES 400000
#define NODE_DIM 256
#define HIDDEN 256
#define OUT_DIM 128
#define PROJ_BLOCKS 628  // 157 m-blocks * 4 n-blocks
#define CONV_BLOCKS 256
#define EDGE_BLOCKS 2048
#define EG 32            // edges per group in edge kernel

typedef __attribute__((ext_vector_type(8))) short short8;
typedef __attribute__((ext_vector_type(4))) float f32x4;
typedef __attribute__((ext_vector_type(16))) float f32x16;

__device__ inline unsigned short f2bf(float f) {
  union { float f; unsigned u; } v; v.f = f;
  unsigned r = (v.u + 0x7FFFu + ((v.u >> 16) & 1u)) >> 16;
  return (unsigned short)r;
}

// async global->LDS, 16B per lane; LDS dst = wave-uniform base + lane*16.
__device__ inline void gload_lds16(const void* g, const void* l) {
  __builtin_amdgcn_global_load_lds(
      (const __attribute__((address_space(1))) unsigned int*)(unsigned long long)g,
      (__attribute__((address_space(3))) unsigned int*)(unsigned int)(unsigned long long)l,
      16, 0, 0);
}

// ---------------- C storage permutation ----------------
// Natural h (0..255 per half) is stored at P(h) = (h>>5)*32 + ((h>>2)&1)*16
//                                               + ((h>>3)&3)*4 + (h&3).
// This makes the edge kernel's per-lane 16 MFMA-C values (one edge, rows
// h = hblk*32 + 4*hi + (r&3) + 8*(r>>2), r=0..15) a CONTIGUOUS 32-B run at
// ushort offset node*512 + half*256 + hblk*32 + hi*16.

// ---------------- Kernel 1: bf16 MFMA proj GEMM + (optional) attrs->bf16.
// half 0 = x@W_src, half 1 = x@W_dst + b_edge (bias folded here).
__global__ __launch_bounds__(256) void proj_mfma(
    const float* __restrict__ x, const float* __restrict__ We,
    const float* __restrict__ be, unsigned short* __restrict__ C,
    float* __restrict__ partial, const float* __restrict__ attrs,
    unsigned short* __restrict__ attrs_bf) {
  const int tid = threadIdx.x;
  if (blockIdx.x >= PROJ_BLOCKS) {
    // convert attrs fp32 -> bf16 (only launched when ws has room)
    const int nt = CONV_BLOCKS * 256;
    const int total4 = 4 * N_EDGES * 16 / 4;
    for (int i = (blockIdx.x - PROJ_BLOCKS) * 256 + tid; i < total4; i += nt) {
      float4 v = ((const float4*)attrs)[i];
      ushort4 o;
      o.x = f2bf(v.x); o.y = f2bf(v.y); o.z = f2bf(v.z); o.w = f2bf(v.w);
      ((ushort4*)attrs_bf)[i] = o;
    }
    return;
  }
  if (blockIdx.x == 0) {
    for (int i = tid; i < 4 * HIDDEN; i += 256) partial[i] = 0.f;
  }
  const int bm = blockIdx.x >> 2;
  const int bn = blockIdx.x & 3;
  const int row0 = bm * 128;
  const int col0 = bn * 128;          // 0,128,256,384
  const int half = col0 >> 8;         // 0: W_src, 1: W_dst
  const int ncol0 = col0 & 255;       // 0 or 128 within half
  const int lane = tid & 63, wave = tid >> 6;
  const int q = lane >> 4, c = lane & 15;
  const int wm = wave >> 1, wn = wave & 1;

  __shared__ unsigned short As[128][32];  // [m][k]
  __shared__ unsigned short Bs[128][32];  // [local n][k] (permuted, transposed W)

  f32x4 acc[4][4];
#pragma unroll
  for (int i = 0; i < 4; ++i)
#pragma unroll
    for (int t = 0; t < 4; ++t) acc[i][t] = (f32x4){0.f, 0.f, 0.f, 0.f};

  const int ar = tid >> 1;            // A stage row 0..127
  const int ak = (tid & 1) * 16;      // A stage k 0/16
  const int bk = tid >> 3;            // B stage k 0..31
  const int bn0 = (tid & 7) * 16;     // B stage n 0..112

  for (int k0 = 0; k0 < NODE_DIM; k0 += 32) {
    {  // A: x rows -> bf16 LDS
      const int r = row0 + ar;
      short8 t0, t1;
      if (r < N_NODES) {
        const float4* src = (const float4*)&x[(size_t)r * NODE_DIM + k0 + ak];
        float4 f0 = src[0], f1 = src[1], f2 = src[2], f3 = src[3];
        t0[0]=f2bf(f0.x); t0[1]=f2bf(f0.y); t0[2]=f2bf(f0.z); t0[3]=f2bf(f0.w);
        t0[4]=f2bf(f1.x); t0[5]=f2bf(f1.y); t0[6]=f2bf(f1.z); t0[7]=f2bf(f1.w);
        t1[0]=f2bf(f2.x); t1[1]=f2bf(f2.y); t1[2]=f2bf(f2.z); t1[3]=f2bf(f2.w);
        t1[4]=f2bf(f3.x); t1[5]=f2bf(f3.y); t1[6]=f2bf(f3.z); t1[7]=f2bf(f3.w);
      } else {
#pragma unroll
        for (int j = 0; j < 8; ++j) { t0[j] = 0; t1[j] = 0; }
      }
      *(short8*)&As[ar][ak] = t0;
      *(short8*)&As[ar][ak + 8] = t1;
    }
    {  // B: We rows -> transposed + column-permuted bf16 LDS.
      // W column wc (0..127 local) is placed at local col
      // ln = (wc&64) + (wc&3)*16 + ((wc>>5)&1)*8 + ((wc>>3)&3)*2 + ((wc>>2)&1)
      // so the epilogue's 4 t-values land at consecutive P() addresses.
      const float4* src = (const float4*)&We[(size_t)(half * 256 + k0 + bk) * HIDDEN + ncol0 + bn0];
#pragma unroll
      for (int v = 0; v < 4; ++v) {
        float4 f = src[v];
        const float fv[4] = {f.x, f.y, f.z, f.w};
#pragma unroll
        for (int comp = 0; comp < 4; ++comp) {
          const int wc = bn0 + v * 4 + comp;
          const int ln = (wc & 64) + (wc & 3) * 16 + ((wc >> 5) & 1) * 8 +
                         ((wc >> 3) & 3) * 2 + ((wc >> 2) & 1);
          Bs[ln][bk] = f2bf(fv[comp]);
        }
      }
    }
    __syncthreads();
    short8 Af[4], Bf[4];
#pragma unroll
    for (int i = 0; i < 4; ++i) Af[i] = *(const short8*)&As[wm * 64 + i * 16 + c][q * 8];
#pragma unroll
    for (int t = 0; t < 4; ++t) Bf[t] = *(const short8*)&Bs[wn * 64 + t * 16 + c][q * 8];
#pragma unroll
    for (int i = 0; i < 4; ++i)
#pragma unroll
      for (int t = 0; t < 4; ++t)
        acc[i][t] = __builtin_amdgcn_mfma_f32_16x16x32_bf16(Af[i], Bf[t], acc[i][t], 0, 0, 0);
    __syncthreads();
  }

  // epilogue: local col lc = wn*64 + t*16 + c holds W column
  // wc = wn*64 + (c>>3)*32 + ((c>>1)&3)*8 + (c&1)*4 + t  (natural h),
  // stored at P(wc) = ncol0 + wn*64 + (c>>3)*32 + (c&1)*16 + ((c>>1)&3)*4 + t.
  const int hb1 = c >> 3, q2v = (c >> 1) & 3, chi = c & 1;
  const int Abase = ncol0 + wn * 64 + hb1 * 32 + chi * 16 + q2v * 4;  // storage
  const int hnat  = ncol0 + wn * 64 + hb1 * 32 + q2v * 8 + chi * 4;   // natural h
  float biasv[4] = {0.f, 0.f, 0.f, 0.f};
  if (half) {
#pragma unroll
    for (int t = 0; t < 4; ++t) biasv[t] = be[hnat + t];
  }
#pragma unroll
  for (int i = 0; i < 4; ++i) {
#pragma unroll
    for (int r = 0; r < 4; ++r) {
      const int node = row0 + wm * 64 + i * 16 + q * 4 + r;
      if (node < N_NODES) {
        ushort4 o;
        o.x = f2bf(acc[i][0][r] + biasv[0]);
        o.y = f2bf(acc[i][1][r] + biasv[1]);
        o.z = f2bf(acc[i][2][r] + biasv[2]);
        o.w = f2bf(acc[i][3][r] + biasv[3]);
        *(ushort4*)&C[(size_t)node * 512 + half * 256 + Abase] = o;
      }
    }
  }
}

// ---------------- Kernel 2: 32x32x16 MFMA fused gather + attr-GEMM + relu + mean.
// M = h (32-block), N = 32 edges, K = 16 attrs (full K utilization).
// base (src+dst proj) is folded into the MFMA C operand.
// Per lane: one edge, 16 h-values -> one contiguous 32-B gather per half.
template <bool PRE>
__global__ __launch_bounds__(256) void edge_mfma(
    const unsigned short* __restrict__ C, const int* __restrict__ ei,
    const float* __restrict__ attrs_f, const unsigned short* __restrict__ attrs_b,
    const float* __restrict__ We, float* __restrict__ partial) {
  const int tid = threadIdx.x;
  const int lane = tid & 63, wave = tid >> 6;
  const int le = lane & 31;   // edge slot within group (N col) / h-row for A
  const int hi = lane >> 5;   // k-half for A/B frags; hi for gather/output rows
  const int fam = blockIdx.x & 1;
  const int hblk = fam * 4 + wave;   // 0..7 (32-h block)
  const int hbase = hblk * 32;

  // A-frag: W_attr^T. A[m=h_local][k]: lane holds h = hbase+le, k = hi*8+j.
  short8 aW;
#pragma unroll
  for (int j = 0; j < 8; ++j)
    aW[j] = (short)f2bf(We[(size_t)(512 + hi * 8 + j) * HIDDEN + hbase + le]);

  f32x16 acc[4];
#pragma unroll
  for (int b = 0; b < 4; ++b)
#pragma unroll
    for (int r = 0; r < 16; ++r) acc[b][r] = 0.f;

  // double-buffered attrs staging: [buf][b][512 ushorts = 64 lanes * 8]
  __shared__ unsigned short attr_s[2][4][512];
  // staging lane i fetches chunk (edge=i&31, khalf=i>>5) so reader lane l
  // reads its own chunk at linear offset l*16 B (conflict-free ds_read_b128).
  const size_t sgoff = (size_t)(le * 16 + hi * 8);

  const int ngroups = N_EDGES / EG;        // 12500
  const int stride = gridDim.x >> 1;       // 1024
  const int g0 = blockIdx.x >> 1;

  int buf = 0;
  int ns, nd;
  {
    if constexpr (PRE) {
      const unsigned short* gp =
          attrs_b + ((size_t)wave * N_EDGES + (size_t)g0 * EG) * 16 + sgoff;
      gload_lds16(gp, &attr_s[0][wave][0]);
    }
    ns = ei[g0 * EG + le];
    nd = ei[N_EDGES + g0 * EG + le];
  }

  for (int g = g0; g < ngroups; g += stride) {
    const int gn = g + stride;
    const int gsafe = (gn < ngroups) ? gn : g;  // clamp: keeps vmcnt counts exact

    // gathers for current group (indices prefetched last iteration)
    const size_t so = (size_t)ns * 512 + hbase + hi * 16;
    const size_t dofs = (size_t)nd * 512 + 256 + hbase + hi * 16;
    const uint4 s0 = *(const uint4*)(C + so);
    const uint4 s1 = *(const uint4*)(C + so + 8);
    const uint4 d0 = *(const uint4*)(C + dofs);
    const uint4 d1 = *(const uint4*)(C + dofs + 8);
    // prefetch next group's indices (always issued -> vmcnt count invariant)
    const int ns2 = ei[gsafe * EG + le];
    const int nd2 = ei[N_EDGES + gsafe * EG + le];

    short8 Bb[4];
    if constexpr (PRE) {
      // outstanding: stage_cur(1, oldest) + gathers(4) + ei(2) = 7.
      // vmcnt(6) guarantees stage_cur complete; gathers/ei stay in flight.
      asm volatile("s_waitcnt vmcnt(6)" ::: "memory");
      __builtin_amdgcn_s_barrier();
      // stage NEXT group (after barrier: previous readers of buf^1 are done)
      {
        const unsigned short* gp =
            attrs_b + ((size_t)wave * N_EDGES + (size_t)gsafe * EG) * 16 + sgoff;
        gload_lds16(gp, &attr_s[buf ^ 1][wave][0]);
      }
#pragma unroll
      for (int b = 0; b < 4; ++b)
        Bb[b] = *(const short8*)&attr_s[buf][b][(size_t)lane * 8];
    } else {
#pragma unroll
      for (int b = 0; b < 4; ++b) {
        const size_t aoff =
            ((size_t)b * N_EDGES + (size_t)g * EG + le) * 16 + hi * 8;
        const float4 a0 = *(const float4*)(attrs_f + aoff);
        const float4 a1 = *(const float4*)(attrs_f + aoff + 4);
        short8 bb;
        bb[0]=f2bf(a0.x); bb[1]=f2bf(a0.y); bb[2]=f2bf(a0.z); bb[3]=f2bf(a0.w);
        bb[4]=f2bf(a1.x); bb[5]=f2bf(a1.y); bb[6]=f2bf(a1.z); bb[7]=f2bf(a1.w);
        Bb[b] = bb;
      }
    }

    // base = src + dst, unpacked straight into MFMA C-operand order (r=0..15)
    f32x16 base;
    base[0]  = __uint_as_float(s0.x << 16)        + __uint_as_float(d0.x << 16);
    base[1]  = __uint_as_float(s0.x & 0xFFFF0000u) + __uint_as_float(d0.x & 0xFFFF0000u);
    base[2]  = __uint_as_float(s0.y << 16)        + __uint_as_float(d0.y << 16);
    base[3]  = __uint_as_float(s0.y & 0xFFFF0000u) + __uint_as_float(d0.y & 0xFFFF0000u);
    base[4]  = __uint_as_float(s0.z << 16)        + __uint_as_float(d0.z << 16);
    base[5]  = __uint_as_float(s0.z & 0xFFFF0000u) + __uint_as_float(d0.z & 0xFFFF0000u);
    base[6]  = __uint_as_float(s0.w << 16)        + __uint_as_float(d0.w << 16);
    base[7]  = __uint_as_float(s0.w & 0xFFFF0000u) + __uint_as_float(d0.w & 0xFFFF0000u);
    base[8]  = __uint_as_float(s1.x << 16)        + __uint_as_float(d1.x << 16);
    base[9]  = __uint_as_float(s1.x & 0xFFFF0000u) + __uint_as_float(d1.x & 0xFFFF0000u);
    base[10] = __uint_as_float(s1.y << 16)        + __uint_as_float(d1.y << 16);
    base[11] = __uint_as_float(s1.y & 0xFFFF0000u) + __uint_as_float(d1.y & 0xFFFF0000u);
    base[12] = __uint_as_float(s1.z << 16)        + __uint_as_float(d1.z << 16);
    base[13] = __uint_as_float(s1.z & 0xFFFF0000u) + __uint_as_float(d1.z & 0xFFFF0000u);
    base[14] = __uint_as_float(s1.w << 16)        + __uint_as_float(d1.w << 16);
    base[15] = __uint_as_float(s1.w & 0xFFFF0000u) + __uint_as_float(d1.w & 0xFFFF0000u);

#pragma unroll
    for (int b = 0; b < 4; ++b) {
      f32x16 S = __builtin_amdgcn_mfma_f32_32x32x16_bf16(aW, Bb[b], base, 0, 0, 0);
#pragma unroll
      for (int r = 0; r < 16; ++r) acc[b][r] += fmaxf(S[r], 0.f);
    }

    ns = ns2; nd = nd2; buf ^= 1;
  }

  // reduce over edges = over the 32 lanes of each hi-half (butterfly all-reduce)
#pragma unroll
  for (int b = 0; b < 4; ++b)
#pragma unroll
    for (int r = 0; r < 16; ++r) {
      float v = acc[b][r];
      v += __shfl_xor(v, 1, 64);
      v += __shfl_xor(v, 2, 64);
      v += __shfl_xor(v, 4, 64);
      v += __shfl_xor(v, 8, 64);
      v += __shfl_xor(v, 16, 64);
      acc[b][r] = v;
    }
  if (le == 0) {  // lanes 0 (hi=0) and 32 (hi=1)
#pragma unroll
    for (int b = 0; b < 4; ++b)
#pragma unroll
      for (int r = 0; r < 16; ++r) {
        const int h = hbase + (r & 3) + 8 * (r >> 2) + 4 * hi;  // natural h
        atomicAdd(&partial[b * HIDDEN + h], acc[b][r]);
      }
  }
}

// ---------------- Kernel 3: out[b,o] = (S[b,:]/E) @ W_graph + b_graph
__global__ __launch_bounds__(256) void graph_out(
    const float* __restrict__ partial, const float* __restrict__ Wg,
    const float* __restrict__ bg, float* __restrict__ out) {
  const int o = blockIdx.x;    // 0..127
  const int hh = threadIdx.x;  // 0..255
  const int lane = hh & 63, wave = hh >> 6;
  const float w = Wg[(size_t)hh * OUT_DIM + o];
  float v[4];
#pragma unroll
  for (int b = 0; b < 4; ++b) v[b] = partial[b * HIDDEN + hh] * w;
#pragma unroll
  for (int off = 32; off >= 1; off >>= 1)
#pragma unroll
    for (int b = 0; b < 4; ++b) v[b] += __shfl_down(v[b], off, 64);
  __shared__ float red[4][4];
  if (lane == 0)
#pragma unroll
    for (int b = 0; b < 4; ++b) red[wave][b] = v[b];
  __syncthreads();
  if (hh < 4) {
    float s = red[0][hh] + red[1][hh] + red[2][hh] + red[3][hh];
    out[hh * OUT_DIM + o] = s * (1.0f / (float)N_EDGES) + bg[o];
  }
}

extern "C" void kernel_launch(void* const* d_in, const int* in_sizes, int n_in,
                              void* d_out, int out_size, void* d_ws, size_t ws_size,
                              hipStream_t stream) {
  const float* x  = (const float*)d_in[0];
  const int*   ei = (const int*)d_in[1];
  const float* ea = (const float*)d_in[2];
  const float* We = (const float*)d_in[3];
  const float* be = (const float*)d_in[4];
  const float* Wg = (const float*)d_in[5];
  const float* bg = (const float*)d_in[6];
  float* out = (float*)d_out;

  const size_t C_bytes = (size_t)N_NODES * 512 * 2;         // 20.48 MB
  const size_t A_bytes = (size_t)4 * N_EDGES * 16 * 2;      // 51.2 MB
  unsigned short* C = (unsigned short*)d_ws;
  const bool pre = ws_size >= C_bytes + A_bytes + 4096;
  unsigned short* attrs_bf = pre ? (unsigned short*)((char*)d_ws + C_bytes) : nullptr;
  float* partial = (float*)((char*)d_ws + (pre ? C_bytes + A_bytes : C_bytes));

  const int grid1 = pre ? PROJ_BLOCKS + CONV_BLOCKS : PROJ_BLOCKS;
  proj_mfma<<<grid1, 256, 0, stream>>>(x, We, be, C, partial, ea, attrs_bf);
  if (pre)
    edge_mfma<true><<<EDGE_BLOCKS, 256, 0, stream>>>(C, ei, nullptr, attrs_bf, We, partial);
  else
    edge_mfma<false><<<EDGE_BLOCKS, 256, 0, stream>>>(C, ei, ea, nullptr, We, partial);
  graph_out<<<128, 256, 0, stream>>>(partial, Wg, bg, out);
}

// Round 2
// 434.587 us; speedup vs baseline: 1.0072x; 1.0072x over previous
//
#include <hip/hip_runtime.h>

#define N_NODES 20000
#define N_EDGES 400000
#define NODE_DIM 256
#define HIDDEN 256
#define OUT_DIM 128
#define PROJ_BLOCKS 628  // 157 m-blocks * 4 n-blocks
#define CONV_BLOCKS 256
#define EDGE_BLOCKS 2048
#define EG 32            // edges per group in edge kernel

typedef __attribute__((ext_vector_type(8))) short short8;
typedef __attribute__((ext_vector_type(4))) float f32x4;
typedef __attribute__((ext_vector_type(16))) float f32x16;

__device__ inline unsigned short f2bf(float f) {
  union { float f; unsigned u; } v; v.f = f;
  unsigned r = (v.u + 0x7FFFu + ((v.u >> 16) & 1u)) >> 16;
  return (unsigned short)r;
}

// ---------------- C storage permutation ----------------
// Natural h (0..255 per half) is stored at P(h) = (h>>5)*32 + ((h>>2)&1)*16
//                                               + ((h>>3)&3)*4 + (h&3).
// This makes the edge kernel's per-lane 16 MFMA-C values (one edge, rows
// h = hblk*32 + 4*hi + (r&3) + 8*(r>>2), r=0..15) a CONTIGUOUS 32-B run at
// ushort offset node*512 + half*256 + hblk*32 + hi*16.
// (Layouts verified by harness pass in previous round.)

// ---------------- Kernel 1: bf16 MFMA proj GEMM + (optional) attrs->bf16.
// half 0 = x@W_src, half 1 = x@W_dst + b_edge (bias folded here).
__global__ __launch_bounds__(256) void proj_mfma(
    const float* __restrict__ x, const float* __restrict__ We,
    const float* __restrict__ be, unsigned short* __restrict__ C,
    float* __restrict__ partial, const float* __restrict__ attrs,
    unsigned short* __restrict__ attrs_bf) {
  const int tid = threadIdx.x;
  if (blockIdx.x >= PROJ_BLOCKS) {
    // convert attrs fp32 -> bf16 (only launched when ws has room)
    const int nt = CONV_BLOCKS * 256;
    const int total4 = 4 * N_EDGES * 16 / 4;
    for (int i = (blockIdx.x - PROJ_BLOCKS) * 256 + tid; i < total4; i += nt) {
      float4 v = ((const float4*)attrs)[i];
      ushort4 o;
      o.x = f2bf(v.x); o.y = f2bf(v.y); o.z = f2bf(v.z); o.w = f2bf(v.w);
      ((ushort4*)attrs_bf)[i] = o;
    }
    return;
  }
  if (blockIdx.x == 0) {
    for (int i = tid; i < 4 * HIDDEN; i += 256) partial[i] = 0.f;
  }
  const int bm = blockIdx.x >> 2;
  const int bn = blockIdx.x & 3;
  const int row0 = bm * 128;
  const int col0 = bn * 128;          // 0,128,256,384
  const int half = col0 >> 8;         // 0: W_src, 1: W_dst
  const int ncol0 = col0 & 255;       // 0 or 128 within half
  const int lane = tid & 63, wave = tid >> 6;
  const int q = lane >> 4, c = lane & 15;
  const int wm = wave >> 1, wn = wave & 1;

  __shared__ unsigned short As[128][32];  // [m][k]
  __shared__ unsigned short Bs[128][32];  // [local n][k] (permuted, transposed W)

  f32x4 acc[4][4];
#pragma unroll
  for (int i = 0; i < 4; ++i)
#pragma unroll
    for (int t = 0; t < 4; ++t) acc[i][t] = (f32x4){0.f, 0.f, 0.f, 0.f};

  const int ar = tid >> 1;            // A stage row 0..127
  const int ak = (tid & 1) * 16;      // A stage k 0/16
  const int bk = tid >> 3;            // B stage k 0..31
  const int bn0 = (tid & 7) * 16;     // B stage n 0..112

  for (int k0 = 0; k0 < NODE_DIM; k0 += 32) {
    {  // A: x rows -> bf16 LDS
      const int r = row0 + ar;
      short8 t0, t1;
      if (r < N_NODES) {
        const float4* src = (const float4*)&x[(size_t)r * NODE_DIM + k0 + ak];
        float4 f0 = src[0], f1 = src[1], f2 = src[2], f3 = src[3];
        t0[0]=f2bf(f0.x); t0[1]=f2bf(f0.y); t0[2]=f2bf(f0.z); t0[3]=f2bf(f0.w);
        t0[4]=f2bf(f1.x); t0[5]=f2bf(f1.y); t0[6]=f2bf(f1.z); t0[7]=f2bf(f1.w);
        t1[0]=f2bf(f2.x); t1[1]=f2bf(f2.y); t1[2]=f2bf(f2.z); t1[3]=f2bf(f2.w);
        t1[4]=f2bf(f3.x); t1[5]=f2bf(f3.y); t1[6]=f2bf(f3.z); t1[7]=f2bf(f3.w);
      } else {
#pragma unroll
        for (int j = 0; j < 8; ++j) { t0[j] = 0; t1[j] = 0; }
      }
      *(short8*)&As[ar][ak] = t0;
      *(short8*)&As[ar][ak + 8] = t1;
    }
    {  // B: We rows -> transposed + column-permuted bf16 LDS.
      const float4* src = (const float4*)&We[(size_t)(half * 256 + k0 + bk) * HIDDEN + ncol0 + bn0];
#pragma unroll
      for (int v = 0; v < 4; ++v) {
        float4 f = src[v];
        const float fv[4] = {f.x, f.y, f.z, f.w};
#pragma unroll
        for (int comp = 0; comp < 4; ++comp) {
          const int wc = bn0 + v * 4 + comp;
          const int ln = (wc & 64) + (wc & 3) * 16 + ((wc >> 5) & 1) * 8 +
                         ((wc >> 3) & 3) * 2 + ((wc >> 2) & 1);
          Bs[ln][bk] = f2bf(fv[comp]);
        }
      }
    }
    __syncthreads();
    short8 Af[4], Bf[4];
#pragma unroll
    for (int i = 0; i < 4; ++i) Af[i] = *(const short8*)&As[wm * 64 + i * 16 + c][q * 8];
#pragma unroll
    for (int t = 0; t < 4; ++t) Bf[t] = *(const short8*)&Bs[wn * 64 + t * 16 + c][q * 8];
#pragma unroll
    for (int i = 0; i < 4; ++i)
#pragma unroll
      for (int t = 0; t < 4; ++t)
        acc[i][t] = __builtin_amdgcn_mfma_f32_16x16x32_bf16(Af[i], Bf[t], acc[i][t], 0, 0, 0);
    __syncthreads();
  }

  // epilogue: local col lc = wn*64 + t*16 + c holds W column
  // wc = wn*64 + (c>>3)*32 + ((c>>1)&3)*8 + (c&1)*4 + t  (natural h),
  // stored at P(wc) = ncol0 + wn*64 + (c>>3)*32 + (c&1)*16 + ((c>>1)&3)*4 + t.
  const int hb1 = c >> 3, q2v = (c >> 1) & 3, chi = c & 1;
  const int Abase = ncol0 + wn * 64 + hb1 * 32 + chi * 16 + q2v * 4;  // storage
  const int hnat  = ncol0 + wn * 64 + hb1 * 32 + q2v * 8 + chi * 4;   // natural h
  float biasv[4] = {0.f, 0.f, 0.f, 0.f};
  if (half) {
#pragma unroll
    for (int t = 0; t < 4; ++t) biasv[t] = be[hnat + t];
  }
#pragma unroll
  for (int i = 0; i < 4; ++i) {
#pragma unroll
    for (int r = 0; r < 4; ++r) {
      const int node = row0 + wm * 64 + i * 16 + q * 4 + r;
      if (node < N_NODES) {
        ushort4 o;
        o.x = f2bf(acc[i][0][r] + biasv[0]);
        o.y = f2bf(acc[i][1][r] + biasv[1]);
        o.z = f2bf(acc[i][2][r] + biasv[2]);
        o.w = f2bf(acc[i][3][r] + biasv[3]);
        *(ushort4*)&C[(size_t)node * 512 + half * 256 + Abase] = o;
      }
    }
  }
}

// ---------------- Kernel 2: 32x32x16 MFMA fused gather + attr-GEMM + relu + mean.
// M = h (32-block), N = 32 edges, K = 16 attrs (full K utilization).
// base (src+dst proj) folded into the MFMA C operand.
// Free-running waves (no barriers/LDS); gathers software-pipelined 1 deep,
// edge indices 2 deep, so random-gather latency is covered by a full
// iteration of compute plus cross-wave TLP.
template <bool PRE>
__global__ __launch_bounds__(256) void edge_mfma(
    const unsigned short* __restrict__ C, const int* __restrict__ ei,
    const float* __restrict__ attrs_f, const unsigned short* __restrict__ attrs_b,
    const float* __restrict__ We, float* __restrict__ partial) {
  const int tid = threadIdx.x;
  const int lane = tid & 63, wave = tid >> 6;
  const int le = lane & 31;   // edge slot within group (N col) / h-row for A
  const int hi = lane >> 5;   // k-half for A/B frags; hi selects 16-ushort chunk
  const int fam = blockIdx.x & 1;
  const int hblk = fam * 4 + wave;   // 0..7 (32-h block)
  const int hbase = hblk * 32;

  // A-frag: W_attr^T. A[m=h_local][k]: lane holds h = hbase+le, k = hi*8+j.
  short8 aW;
#pragma unroll
  for (int j = 0; j < 8; ++j)
    aW[j] = (short)f2bf(We[(size_t)(512 + hi * 8 + j) * HIDDEN + hbase + le]);

  f32x16 acc[4];
#pragma unroll
  for (int b = 0; b < 4; ++b)
#pragma unroll
    for (int r = 0; r < 16; ++r) acc[b][r] = 0.f;

  const int ngroups = N_EDGES / EG;        // 12500
  const int stride = gridDim.x >> 1;       // 1024
  const int g0 = blockIdx.x >> 1;

  // ---- pipeline prologue ----
  // indices for g0, gathers for g0, indices for g0+stride
  int ns = ei[g0 * EG + le];
  int nd = ei[N_EDGES + g0 * EG + le];
  uint4 cs0, cs1, cd0, cd1;
  {
    const size_t so = (size_t)ns * 512 + hbase + hi * 16;
    const size_t dofs = (size_t)nd * 512 + 256 + hbase + hi * 16;
    cs0 = *(const uint4*)(C + so);
    cs1 = *(const uint4*)(C + so + 8);
    cd0 = *(const uint4*)(C + dofs);
    cd1 = *(const uint4*)(C + dofs + 8);
  }
  int nsn = ns, ndn = nd;
  {
    const int g1 = g0 + stride;
    if (g1 < ngroups) {
      nsn = ei[g1 * EG + le];
      ndn = ei[N_EDGES + g1 * EG + le];
    }
  }

  for (int g = g0; g < ngroups; g += stride) {
    const int gn = g + stride;
    const bool has_next = gn < ngroups;

    // attrs for current group: coalesced 16B/lane
    short8 Bb[4];
    if constexpr (PRE) {
#pragma unroll
      for (int b = 0; b < 4; ++b)
        Bb[b] = *(const short8*)&attrs_b[((size_t)b * N_EDGES + (size_t)g * EG + le) * 16 + hi * 8];
    } else {
#pragma unroll
      for (int b = 0; b < 4; ++b) {
        const size_t aoff = ((size_t)b * N_EDGES + (size_t)g * EG + le) * 16 + hi * 8;
        const float4 a0 = *(const float4*)(attrs_f + aoff);
        const float4 a1 = *(const float4*)(attrs_f + aoff + 4);
        short8 bb;
        bb[0]=f2bf(a0.x); bb[1]=f2bf(a0.y); bb[2]=f2bf(a0.z); bb[3]=f2bf(a0.w);
        bb[4]=f2bf(a1.x); bb[5]=f2bf(a1.y); bb[6]=f2bf(a1.z); bb[7]=f2bf(a1.w);
        Bb[b] = bb;
      }
    }

    // issue NEXT group's gathers (indices already in regs; clamp keeps addr valid)
    uint4 xs0, xs1, xd0, xd1;
    {
      const int nsl = has_next ? nsn : ns;
      const int ndl = has_next ? ndn : nd;
      const size_t so = (size_t)nsl * 512 + hbase + hi * 16;
      const size_t dofs = (size_t)ndl * 512 + 256 + hbase + hi * 16;
      xs0 = *(const uint4*)(C + so);
      xs1 = *(const uint4*)(C + so + 8);
      xd0 = *(const uint4*)(C + dofs);
      xd1 = *(const uint4*)(C + dofs + 8);
    }
    // issue indices for g + 2*stride
    int nsn2 = nsn, ndn2 = ndn;
    {
      const int g2 = gn + stride;
      if (g2 < ngroups) {
        nsn2 = ei[g2 * EG + le];
        ndn2 = ei[N_EDGES + g2 * EG + le];
      }
    }

    // base = src + dst, unpacked straight into MFMA C-operand order (r=0..15)
    f32x16 base;
    base[0]  = __uint_as_float(cs0.x << 16)         + __uint_as_float(cd0.x << 16);
    base[1]  = __uint_as_float(cs0.x & 0xFFFF0000u) + __uint_as_float(cd0.x & 0xFFFF0000u);
    base[2]  = __uint_as_float(cs0.y << 16)         + __uint_as_float(cd0.y << 16);
    base[3]  = __uint_as_float(cs0.y & 0xFFFF0000u) + __uint_as_float(cd0.y & 0xFFFF0000u);
    base[4]  = __uint_as_float(cs0.z << 16)         + __uint_as_float(cd0.z << 16);
    base[5]  = __uint_as_float(cs0.z & 0xFFFF0000u) + __uint_as_float(cd0.z & 0xFFFF0000u);
    base[6]  = __uint_as_float(cs0.w << 16)         + __uint_as_float(cd0.w << 16);
    base[7]  = __uint_as_float(cs0.w & 0xFFFF0000u) + __uint_as_float(cd0.w & 0xFFFF0000u);
    base[8]  = __uint_as_float(cs1.x << 16)         + __uint_as_float(cd1.x << 16);
    base[9]  = __uint_as_float(cs1.x & 0xFFFF0000u) + __uint_as_float(cd1.x & 0xFFFF0000u);
    base[10] = __uint_as_float(cs1.y << 16)         + __uint_as_float(cd1.y << 16);
    base[11] = __uint_as_float(cs1.y & 0xFFFF0000u) + __uint_as_float(cd1.y & 0xFFFF0000u);
    base[12] = __uint_as_float(cs1.z << 16)         + __uint_as_float(cd1.z << 16);
    base[13] = __uint_as_float(cs1.z & 0xFFFF0000u) + __uint_as_float(cd1.z & 0xFFFF0000u);
    base[14] = __uint_as_float(cs1.w << 16)         + __uint_as_float(cd1.w << 16);
    base[15] = __uint_as_float(cs1.w & 0xFFFF0000u) + __uint_as_float(cd1.w & 0xFFFF0000u);

#pragma unroll
    for (int b = 0; b < 4; ++b) {
      f32x16 S = __builtin_amdgcn_mfma_f32_32x32x16_bf16(aW, Bb[b], base, 0, 0, 0);
#pragma unroll
      for (int r = 0; r < 16; ++r) acc[b][r] += fmaxf(S[r], 0.f);
    }

    // rotate pipeline
    cs0 = xs0; cs1 = xs1; cd0 = xd0; cd1 = xd1;
    ns = nsn; nd = ndn; nsn = nsn2; ndn = ndn2;
  }

  // reduce over edges = over the 32 lanes of each hi-half (butterfly all-reduce)
#pragma unroll
  for (int b = 0; b < 4; ++b)
#pragma unroll
    for (int r = 0; r < 16; ++r) {
      float v = acc[b][r];
      v += __shfl_xor(v, 1, 64);
      v += __shfl_xor(v, 2, 64);
      v += __shfl_xor(v, 4, 64);
      v += __shfl_xor(v, 8, 64);
      v += __shfl_xor(v, 16, 64);
      acc[b][r] = v;
    }
  if (le == 0) {  // lanes 0 (hi=0) and 32 (hi=1)
#pragma unroll
    for (int b = 0; b < 4; ++b)
#pragma unroll
      for (int r = 0; r < 16; ++r) {
        const int h = hbase + (r & 3) + 8 * (r >> 2) + 4 * hi;  // natural h
        atomicAdd(&partial[b * HIDDEN + h], acc[b][r]);
      }
  }
}

// ---------------- Kernel 3: out[b,o] = (S[b,:]/E) @ W_graph + b_graph
__global__ __launch_bounds__(256) void graph_out(
    const float* __restrict__ partial, const float* __restrict__ Wg,
    const float* __restrict__ bg, float* __restrict__ out) {
  const int o = blockIdx.x;    // 0..127
  const int hh = threadIdx.x;  // 0..255
  const int lane = hh & 63, wave = hh >> 6;
  const float w = Wg[(size_t)hh * OUT_DIM + o];
  float v[4];
#pragma unroll
  for (int b = 0; b < 4; ++b) v[b] = partial[b * HIDDEN + hh] * w;
#pragma unroll
  for (int off = 32; off >= 1; off >>= 1)
#pragma unroll
    for (int b = 0; b < 4; ++b) v[b] += __shfl_down(v[b], off, 64);
  __shared__ float red[4][4];
  if (lane == 0)
#pragma unroll
    for (int b = 0; b < 4; ++b) red[wave][b] = v[b];
  __syncthreads();
  if (hh < 4) {
    float s = red[0][hh] + red[1][hh] + red[2][hh] + red[3][hh];
    out[hh * OUT_DIM + o] = s * (1.0f / (float)N_EDGES) + bg[o];
  }
}

extern "C" void kernel_launch(void* const* d_in, const int* in_sizes, int n_in,
                              void* d_out, int out_size, void* d_ws, size_t ws_size,
                              hipStream_t stream) {
  const float* x  = (const float*)d_in[0];
  const int*   ei = (const int*)d_in[1];
  const float* ea = (const float*)d_in[2];
  const float* We = (const float*)d_in[3];
  const float* be = (const float*)d_in[4];
  const float* Wg = (const float*)d_in[5];
  const float* bg = (const float*)d_in[6];
  float* out = (float*)d_out;

  const size_t C_bytes = (size_t)N_NODES * 512 * 2;         // 20.48 MB
  const size_t A_bytes = (size_t)4 * N_EDGES * 16 * 2;      // 51.2 MB
  unsigned short* C = (unsigned short*)d_ws;
  const bool pre = ws_size >= C_bytes + A_bytes + 4096;
  unsigned short* attrs_bf = pre ? (unsigned short*)((char*)d_ws + C_bytes) : nullptr;
  float* partial = (float*)((char*)d_ws + (pre ? C_bytes + A_bytes : C_bytes));

  const int grid1 = pre ? PROJ_BLOCKS + CONV_BLOCKS : PROJ_BLOCKS;
  proj_mfma<<<grid1, 256, 0, stream>>>(x, We, be, C, partial, ea, attrs_bf);
  if (pre)
    edge_mfma<true><<<EDGE_BLOCKS, 256, 0, stream>>>(C, ei, nullptr, attrs_bf, We, partial);
  else
    edge_mfma<false><<<EDGE_BLOCKS, 256, 0, stream>>>(C, ei, ea, nullptr, We, partial);
  graph_out<<<128, 256, 0, stream>>>(partial, Wg, bg, out);
}

// Round 3
// 292.892 us; speedup vs baseline: 1.4945x; 1.4838x over previous
//
#include <hip/hip_runtime.h>

#define N_NODES 20000
#define N_EDGES 400000
#define NODE_DIM 256
#define HIDDEN 256
#define OUT_DIM 128
#define PROJ_BLOCKS 628  // 157 m-blocks * 4 n-blocks
#define CONV_BLOCKS 256

typedef __attribute__((ext_vector_type(8))) short short8;
typedef __attribute__((ext_vector_type(4))) float f32x4;

__device__ inline unsigned short f2bf(float f) {
  union { float f; unsigned u; } v; v.f = f;
  unsigned r = (v.u + 0x7FFFu + ((v.u >> 16) & 1u)) >> 16;
  return (unsigned short)r;
}

// ---------------- Kernel 1: bf16 MFMA proj GEMM + (optional) attrs->bf16 convert.
// C layout (bf16): C[node][half*256 + n64blk + c*4 + t] where h = n64blk + t*16 + c.
// half 0 = x@W_src, half 1 = x@W_dst + b_edge (bias folded here).
__global__ __launch_bounds__(256) void proj_mfma(
    const float* __restrict__ x, const float* __restrict__ We,
    const float* __restrict__ be, unsigned short* __restrict__ C,
    float* __restrict__ partial, const float* __restrict__ attrs,
    unsigned short* __restrict__ attrs_bf) {
  const int tid = threadIdx.x;
  if (blockIdx.x >= PROJ_BLOCKS) {
    // convert attrs fp32 -> bf16 (only launched when ws has room)
    const int nt = CONV_BLOCKS * 256;
    const int total4 = 4 * N_EDGES * 16 / 4;
    for (int i = (blockIdx.x - PROJ_BLOCKS) * 256 + tid; i < total4; i += nt) {
      float4 v = ((const float4*)attrs)[i];
      ushort4 o;
      o.x = f2bf(v.x); o.y = f2bf(v.y); o.z = f2bf(v.z); o.w = f2bf(v.w);
      ((ushort4*)attrs_bf)[i] = o;
    }
    return;
  }
  if (blockIdx.x == 0) {
    for (int i = tid; i < 4 * HIDDEN; i += 256) partial[i] = 0.f;
  }
  const int bm = blockIdx.x >> 2;
  const int bn = blockIdx.x & 3;
  const int row0 = bm * 128;
  const int col0 = bn * 128;          // 0,128,256,384
  const int half = col0 >> 8;         // 0: W_src, 1: W_dst
  const int ncol0 = col0 & 255;       // 0 or 128 within half
  const int lane = tid & 63, wave = tid >> 6;
  const int q = lane >> 4, c = lane & 15;
  const int wm = wave >> 1, wn = wave & 1;

  __shared__ unsigned short As[128][32];  // [m][k]
  __shared__ unsigned short Bs[128][32];  // [n][k] (transposed W)

  f32x4 acc[4][4];
#pragma unroll
  for (int i = 0; i < 4; ++i)
#pragma unroll
    for (int t = 0; t < 4; ++t) acc[i][t] = (f32x4){0.f, 0.f, 0.f, 0.f};

  const int ar = tid >> 1;            // A stage row 0..127
  const int ak = (tid & 1) * 16;      // A stage k 0/16
  const int bk = tid >> 3;            // B stage k 0..31
  const int bn0 = (tid & 7) * 16;     // B stage n 0..112

  for (int k0 = 0; k0 < NODE_DIM; k0 += 32) {
    {  // A: x rows -> bf16 LDS
      const int r = row0 + ar;
      short8 t0, t1;
      if (r < N_NODES) {
        const float4* src = (const float4*)&x[(size_t)r * NODE_DIM + k0 + ak];
        float4 f0 = src[0], f1 = src[1], f2 = src[2], f3 = src[3];
        t0[0]=f2bf(f0.x); t0[1]=f2bf(f0.y); t0[2]=f2bf(f0.z); t0[3]=f2bf(f0.w);
        t0[4]=f2bf(f1.x); t0[5]=f2bf(f1.y); t0[6]=f2bf(f1.z); t0[7]=f2bf(f1.w);
        t1[0]=f2bf(f2.x); t1[1]=f2bf(f2.y); t1[2]=f2bf(f2.z); t1[3]=f2bf(f2.w);
        t1[4]=f2bf(f3.x); t1[5]=f2bf(f3.y); t1[6]=f2bf(f3.z); t1[7]=f2bf(f3.w);
      } else {
#pragma unroll
        for (int j = 0; j < 8; ++j) { t0[j] = 0; t1[j] = 0; }
      }
      *(short8*)&As[ar][ak] = t0;
      *(short8*)&As[ar][ak + 8] = t1;
    }
    {  // B: We rows -> transposed bf16 LDS
      const float4* src = (const float4*)&We[(size_t)(half * 256 + k0 + bk) * HIDDEN + ncol0 + bn0];
#pragma unroll
      for (int v = 0; v < 4; ++v) {
        float4 f = src[v];
        Bs[bn0 + v * 4 + 0][bk] = f2bf(f.x);
        Bs[bn0 + v * 4 + 1][bk] = f2bf(f.y);
        Bs[bn0 + v * 4 + 2][bk] = f2bf(f.z);
        Bs[bn0 + v * 4 + 3][bk] = f2bf(f.w);
      }
    }
    __syncthreads();
    short8 Af[4], Bf[4];
#pragma unroll
    for (int i = 0; i < 4; ++i) Af[i] = *(const short8*)&As[wm * 64 + i * 16 + c][q * 8];
#pragma unroll
    for (int t = 0; t < 4; ++t) Bf[t] = *(const short8*)&Bs[wn * 64 + t * 16 + c][q * 8];
#pragma unroll
    for (int i = 0; i < 4; ++i)
#pragma unroll
      for (int t = 0; t < 4; ++t)
        acc[i][t] = __builtin_amdgcn_mfma_f32_16x16x32_bf16(Af[i], Bf[t], acc[i][t], 0, 0, 0);
    __syncthreads();
  }

  float biasv[4] = {0.f, 0.f, 0.f, 0.f};
  const int nbase = ncol0 + wn * 64;
  if (half) {
#pragma unroll
    for (int t = 0; t < 4; ++t) biasv[t] = be[nbase + t * 16 + c];
  }
#pragma unroll
  for (int i = 0; i < 4; ++i) {
#pragma unroll
    for (int r = 0; r < 4; ++r) {
      const int node = row0 + wm * 64 + i * 16 + q * 4 + r;
      if (node < N_NODES) {
        ushort4 o;
        o.x = f2bf(acc[i][0][r] + biasv[0]);
        o.y = f2bf(acc[i][1][r] + biasv[1]);
        o.z = f2bf(acc[i][2][r] + biasv[2]);
        o.w = f2bf(acc[i][3][r] + biasv[3]);
        *(ushort4*)&C[(size_t)node * 512 + half * 256 + nbase + c * 4] = o;
      }
    }
  }
}

// ---------------- Kernel 2: MFMA fused gather + attr-GEMM + relu + mean.
// Base gather from permuted bf16 C: per edge-row one uint2 (4 h-values),
// coalesced across the 16 c-lanes of each q-group (128-B segments).
// base folded into the MFMA C operand; edge indices prefetched 1 iter ahead.
template <bool PRE>
__global__ __launch_bounds__(256) void edge_mfma(
    const unsigned short* __restrict__ C, const int* __restrict__ ei,
    const float* __restrict__ attrs_f, const unsigned short* __restrict__ attrs_b,
    const float* __restrict__ We, float* __restrict__ partial) {
  const int tid = threadIdx.x;
  const int lane = tid & 63, wave = tid >> 6;
  const int q = lane >> 4, c = lane & 15;
  const int hb = wave * 64;

  short8 Bf[4];
#pragma unroll
  for (int t = 0; t < 4; ++t) {
    short8 bf;
#pragma unroll
    for (int j = 0; j < 8; ++j) {
      int k = q * 8 + j;
      float w = (k < 16) ? We[(size_t)(512 + k) * HIDDEN + hb + t * 16 + c] : 0.0f;
      bf[j] = (short)f2bf(w);
    }
    Bf[t] = bf;
  }

  f32x4 acc4[4][4];  // [b][t]
#pragma unroll
  for (int b = 0; b < 4; ++b)
#pragma unroll
    for (int t = 0; t < 4; ++t) acc4[b][t] = (f32x4){0.f, 0.f, 0.f, 0.f};

  const int ngroups = N_EDGES / 16;

  // prologue: indices for the first group
  int4 ns4 = *(const int4*)&ei[blockIdx.x * 16 + q * 4];
  int4 nd4 = *(const int4*)&ei[N_EDGES + blockIdx.x * 16 + q * 4];

  for (int g = blockIdx.x; g < ngroups; g += gridDim.x) {
    const int e0 = g * 16;
    const int gn = g + gridDim.x;

    // issue gathers first (indices already in regs)
    uint2 sv[4], dv[4];
    {
      const int nn[4] = {ns4.x, ns4.y, ns4.z, ns4.w};
      const int dd[4] = {nd4.x, nd4.y, nd4.z, nd4.w};
#pragma unroll
      for (int r = 0; r < 4; ++r) {
        sv[r] = *(const uint2*)&C[(size_t)nn[r] * 512 + hb + c * 4];
        dv[r] = *(const uint2*)&C[(size_t)dd[r] * 512 + 256 + hb + c * 4];
      }
    }
    // prefetch next group's indices
    if (gn < ngroups) {
      ns4 = *(const int4*)&ei[gn * 16 + q * 4];
      nd4 = *(const int4*)&ei[N_EDGES + gn * 16 + q * 4];
    }

    short8 Af[4];
    if (PRE) {
      if (q < 2) {
#pragma unroll
        for (int b = 0; b < 4; ++b)
          Af[b] = *(const short8*)&attrs_b[((size_t)b * N_EDGES + e0 + c) * 16 + q * 8];
      } else {
        short8 z;
#pragma unroll
        for (int j = 0; j < 8; ++j) z[j] = 0;
#pragma unroll
        for (int b = 0; b < 4; ++b) Af[b] = z;
      }
    } else {
      if (q < 2) {
#pragma unroll
        for (int b = 0; b < 4; ++b) {
          const size_t off = ((size_t)b * N_EDGES + e0 + c) * 16 + q * 8;
          const float4 a0 = *(const float4*)&attrs_f[off];
          const float4 a1 = *(const float4*)&attrs_f[off + 4];
          short8 af;
          af[0]=f2bf(a0.x); af[1]=f2bf(a0.y); af[2]=f2bf(a0.z); af[3]=f2bf(a0.w);
          af[4]=f2bf(a1.x); af[5]=f2bf(a1.y); af[6]=f2bf(a1.z); af[7]=f2bf(a1.w);
          Af[b] = af;
        }
      } else {
        short8 z;
#pragma unroll
        for (int j = 0; j < 8; ++j) z[j] = 0;
#pragma unroll
        for (int b = 0; b < 4; ++b) Af[b] = z;
      }
    }

    // unpack base = src + dst (bias already folded into dst half)
    f32x4 base4[4];  // [t], component = row r
#pragma unroll
    for (int r = 0; r < 4; ++r) {
      const uint2 s = sv[r], d = dv[r];
      base4[0][r] = __uint_as_float(s.x << 16) + __uint_as_float(d.x << 16);
      base4[1][r] = __uint_as_float(s.x & 0xFFFF0000u) + __uint_as_float(d.x & 0xFFFF0000u);
      base4[2][r] = __uint_as_float(s.y << 16) + __uint_as_float(d.y << 16);
      base4[3][r] = __uint_as_float(s.y & 0xFFFF0000u) + __uint_as_float(d.y & 0xFFFF0000u);
    }

#pragma unroll
    for (int b = 0; b < 4; ++b) {
#pragma unroll
      for (int t = 0; t < 4; ++t) {
        // base folded into MFMA C operand: S = attrs@Wa + base
        f32x4 S = __builtin_amdgcn_mfma_f32_16x16x32_bf16(Af[b], Bf[t], base4[t], 0, 0, 0);
        acc4[b][t][0] += fmaxf(S[0], 0.f);
        acc4[b][t][1] += fmaxf(S[1], 0.f);
        acc4[b][t][2] += fmaxf(S[2], 0.f);
        acc4[b][t][3] += fmaxf(S[3], 0.f);
      }
    }
  }

#pragma unroll
  for (int b = 0; b < 4; ++b)
#pragma unroll
    for (int t = 0; t < 4; ++t) {
      float v = acc4[b][t][0] + acc4[b][t][1] + acc4[b][t][2] + acc4[b][t][3];
      v += __shfl_xor(v, 16, 64);
      v += __shfl_xor(v, 32, 64);
      if (q == 0) atomicAdd(&partial[b * HIDDEN + hb + t * 16 + c], v);
    }
}

// ---------------- Kernel 3: out[b,o] = (S[b,:]/E) @ W_graph + b_graph
__global__ __launch_bounds__(256) void graph_out(
    const float* __restrict__ partial, const float* __restrict__ Wg,
    const float* __restrict__ bg, float* __restrict__ out) {
  const int o = blockIdx.x;    // 0..127
  const int hh = threadIdx.x;  // 0..255
  const int lane = hh & 63, wave = hh >> 6;
  const float w = Wg[(size_t)hh * OUT_DIM + o];
  float v[4];
#pragma unroll
  for (int b = 0; b < 4; ++b) v[b] = partial[b * HIDDEN + hh] * w;
#pragma unroll
  for (int off = 32; off >= 1; off >>= 1)
#pragma unroll
    for (int b = 0; b < 4; ++b) v[b] += __shfl_down(v[b], off, 64);
  __shared__ float red[4][4];
  if (lane == 0)
#pragma unroll
    for (int b = 0; b < 4; ++b) red[wave][b] = v[b];
  __syncthreads();
  if (hh < 4) {
    float s = red[0][hh] + red[1][hh] + red[2][hh] + red[3][hh];
    out[hh * OUT_DIM + o] = s * (1.0f / (float)N_EDGES) + bg[o];
  }
}

extern "C" void kernel_launch(void* const* d_in, const int* in_sizes, int n_in,
                              void* d_out, int out_size, void* d_ws, size_t ws_size,
                              hipStream_t stream) {
  const float* x  = (const float*)d_in[0];
  const int*   ei = (const int*)d_in[1];
  const float* ea = (const float*)d_in[2];
  const float* We = (const float*)d_in[3];
  const float* be = (const float*)d_in[4];
  const float* Wg = (const float*)d_in[5];
  const float* bg = (const float*)d_in[6];
  float* out = (float*)d_out;

  const size_t C_bytes = (size_t)N_NODES * 512 * 2;         // 20.48 MB
  const size_t A_bytes = (size_t)4 * N_EDGES * 16 * 2;      // 51.2 MB
  unsigned short* C = (unsigned short*)d_ws;
  const bool pre = ws_size >= C_bytes + A_bytes + 4096;
  unsigned short* attrs_bf = pre ? (unsigned short*)((char*)d_ws + C_bytes) : nullptr;
  float* partial = (float*)((char*)d_ws + (pre ? C_bytes + A_bytes : C_bytes));

  const int grid1 = pre ? PROJ_BLOCKS + CONV_BLOCKS : PROJ_BLOCKS;
  proj_mfma<<<grid1, 256, 0, stream>>>(x, We, be, C, partial, ea, attrs_bf);
  if (pre)
    edge_mfma<true><<<2048, 256, 0, stream>>>(C, ei, nullptr, attrs_bf, We, partial);
  else
    edge_mfma<false><<<2048, 256, 0, stream>>>(C, ei, ea, nullptr, We, partial);
  graph_out<<<128, 256, 0, stream>>>(partial, Wg, bg, out);
}

// Round 4
// 287.150 us; speedup vs baseline: 1.5244x; 1.0200x over previous
//
#include <hip/hip_runtime.h>

#define N_NODES 20000
#define N_EDGES 400000
#define NODE_DIM 256
#define HIDDEN 256
#define OUT_DIM 128
#define PROJ_BLOCKS 628  // 157 m-blocks * 4 n-blocks
#define CONV_BLOCKS 256

typedef __attribute__((ext_vector_type(8))) short short8;
typedef __attribute__((ext_vector_type(4))) float f32x4;

__device__ inline unsigned short f2bf(float f) {
  union { float f; unsigned u; } v; v.f = f;
  unsigned r = (v.u + 0x7FFFu + ((v.u >> 16) & 1u)) >> 16;
  return (unsigned short)r;
}

// async global->LDS, 16B per lane; LDS dst = wave-uniform base + lane*16.
// (compiled+ran correct on this harness in round 1)
__device__ inline void gload_lds16(const void* g, const void* l) {
  __builtin_amdgcn_global_load_lds(
      (const __attribute__((address_space(1))) unsigned int*)(unsigned long long)g,
      (__attribute__((address_space(3))) unsigned int*)(unsigned int)(unsigned long long)l,
      16, 0, 0);
}

// ---------------- Kernel 0 (tier2): one memory-bound prep pass.
// x fp32 -> bf16; attrs fp32 -> bf16; We[0:512] -> bf16 TRANSPOSED We_t[n][k];
// zero partial.
__global__ __launch_bounds__(256) void prep(
    const float* __restrict__ x, const float* __restrict__ We,
    const float* __restrict__ attrs, unsigned short* __restrict__ xb,
    unsigned short* __restrict__ Wt, unsigned short* __restrict__ ab,
    float* __restrict__ partial) {
  const int tid = threadIdx.x;
  const int gtid = blockIdx.x * 256 + tid;
  const int nt = gridDim.x * 256;
  if (blockIdx.x == 0) {
    for (int i = tid; i < 4 * HIDDEN; i += 256) partial[i] = 0.f;
  }
  const int x4 = N_NODES * NODE_DIM / 4;   // 1,280,000
  const int a4 = 4 * N_EDGES * 16 / 4;     // 6,400,000
  for (int i = gtid; i < x4 + a4; i += nt) {
    float4 v;
    unsigned short* dst;
    if (i < x4) {
      v = ((const float4*)x)[i];
      dst = xb + (size_t)i * 4;
    } else {
      v = ((const float4*)attrs)[i - x4];
      dst = ab + (size_t)(i - x4) * 4;
    }
    ushort4 o;
    o.x = f2bf(v.x); o.y = f2bf(v.y); o.z = f2bf(v.z); o.w = f2bf(v.w);
    *(ushort4*)dst = o;
  }
  // We_t[half*256 + n][k] = We[half*256 + k][n], k in [0,256)
  for (int i = gtid; i < 2 * 256 * 64; i += nt) {
    const int row = i >> 6;          // half*256 + n
    const int k4 = (i & 63) * 4;
    const int half = row >> 8, n = row & 255;
    ushort4 o;
    o.x = f2bf(We[(size_t)(half * 256 + k4 + 0) * HIDDEN + n]);
    o.y = f2bf(We[(size_t)(half * 256 + k4 + 1) * HIDDEN + n]);
    o.z = f2bf(We[(size_t)(half * 256 + k4 + 2) * HIDDEN + n]);
    o.w = f2bf(We[(size_t)(half * 256 + k4 + 3) * HIDDEN + n]);
    *(ushort4*)&Wt[(size_t)row * 256 + k4] = o;
  }
}

// ---------------- Kernel 1 (tier2): pure-bf16 proj GEMM, m97 pattern.
// global_load_lds width-16 staging of A (x_bf) and B (We_t), linear LDS,
// 2 barriers per 32-k step, 16 MFMA. Output layout and epilogue identical
// to the verified old proj_mfma (bit-identical C).
__global__ __launch_bounds__(256) void proj_bf(
    const unsigned short* __restrict__ xb, const unsigned short* __restrict__ Wt,
    const float* __restrict__ be, unsigned short* __restrict__ C) {
  const int tid = threadIdx.x;
  const int bm = blockIdx.x >> 2;
  const int bn = blockIdx.x & 3;
  const int row0 = bm * 128;
  const int col0 = bn * 128;          // 0,128,256,384
  const int half = col0 >> 8;         // 0: W_src, 1: W_dst
  const int ncol0 = col0 & 255;       // 0 or 128 within half
  const int lane = tid & 63, wave = tid >> 6;
  const int q = lane >> 4, c = lane & 15;
  const int wm = wave >> 1, wn = wave & 1;

  __shared__ unsigned short As[128][32];  // [m][k] linear (gload_lds dst)
  __shared__ unsigned short Bs[128][32];  // [local n][k] linear

  f32x4 acc[4][4];
#pragma unroll
  for (int i = 0; i < 4; ++i)
#pragma unroll
    for (int t = 0; t < 4; ++t) acc[i][t] = (f32x4){0.f, 0.f, 0.f, 0.f};

  // staging map: wave w, lane i covers LDS row w*16 + i/4 (+64 in round 1),
  // k-chunk (i%4)*8 ushorts. dst = base + lane*16B (linear, matches).
  const int sm = wave * 16 + (lane >> 2);
  const int skc = (lane & 3) * 8;
  int ra0 = row0 + sm;       if (ra0 >= N_NODES) ra0 = 0;  // clamp: garbage rows never stored
  int ra1 = row0 + 64 + sm;  if (ra1 >= N_NODES) ra1 = 0;
  const int nb0 = half * 256 + ncol0 + sm;
  const int nb1 = nb0 + 64;

  for (int k0 = 0; k0 < NODE_DIM; k0 += 32) {
    gload_lds16(xb + (size_t)ra0 * 256 + k0 + skc, &As[wave * 16][0]);
    gload_lds16(xb + (size_t)ra1 * 256 + k0 + skc, &As[64 + wave * 16][0]);
    gload_lds16(Wt + (size_t)nb0 * 256 + k0 + skc, &Bs[wave * 16][0]);
    gload_lds16(Wt + (size_t)nb1 * 256 + k0 + skc, &Bs[64 + wave * 16][0]);
    __syncthreads();
    short8 Af[4], Bf[4];
#pragma unroll
    for (int i = 0; i < 4; ++i) Af[i] = *(const short8*)&As[wm * 64 + i * 16 + c][q * 8];
#pragma unroll
    for (int t = 0; t < 4; ++t) Bf[t] = *(const short8*)&Bs[wn * 64 + t * 16 + c][q * 8];
#pragma unroll
    for (int i = 0; i < 4; ++i)
#pragma unroll
      for (int t = 0; t < 4; ++t)
        acc[i][t] = __builtin_amdgcn_mfma_f32_16x16x32_bf16(Af[i], Bf[t], acc[i][t], 0, 0, 0);
    __syncthreads();
  }

  float biasv[4] = {0.f, 0.f, 0.f, 0.f};
  const int nbase = ncol0 + wn * 64;
  if (half) {
#pragma unroll
    for (int t = 0; t < 4; ++t) biasv[t] = be[nbase + t * 16 + c];
  }
#pragma unroll
  for (int i = 0; i < 4; ++i) {
#pragma unroll
    for (int r = 0; r < 4; ++r) {
      const int node = row0 + wm * 64 + i * 16 + q * 4 + r;
      if (node < N_NODES) {
        ushort4 o;
        o.x = f2bf(acc[i][0][r] + biasv[0]);
        o.y = f2bf(acc[i][1][r] + biasv[1]);
        o.z = f2bf(acc[i][2][r] + biasv[2]);
        o.w = f2bf(acc[i][3][r] + biasv[3]);
        *(ushort4*)&C[(size_t)node * 512 + half * 256 + nbase + c * 4] = o;
      }
    }
  }
}

// ---------------- Fallback kernel 1: old fp32-staged proj GEMM + attrs conv.
__global__ __launch_bounds__(256) void proj_mfma(
    const float* __restrict__ x, const float* __restrict__ We,
    const float* __restrict__ be, unsigned short* __restrict__ C,
    float* __restrict__ partial, const float* __restrict__ attrs,
    unsigned short* __restrict__ attrs_bf) {
  const int tid = threadIdx.x;
  if (blockIdx.x >= PROJ_BLOCKS) {
    const int nt = CONV_BLOCKS * 256;
    const int total4 = 4 * N_EDGES * 16 / 4;
    for (int i = (blockIdx.x - PROJ_BLOCKS) * 256 + tid; i < total4; i += nt) {
      float4 v = ((const float4*)attrs)[i];
      ushort4 o;
      o.x = f2bf(v.x); o.y = f2bf(v.y); o.z = f2bf(v.z); o.w = f2bf(v.w);
      ((ushort4*)attrs_bf)[i] = o;
    }
    return;
  }
  if (blockIdx.x == 0) {
    for (int i = tid; i < 4 * HIDDEN; i += 256) partial[i] = 0.f;
  }
  const int bm = blockIdx.x >> 2;
  const int bn = blockIdx.x & 3;
  const int row0 = bm * 128;
  const int col0 = bn * 128;
  const int half = col0 >> 8;
  const int ncol0 = col0 & 255;
  const int lane = tid & 63, wave = tid >> 6;
  const int q = lane >> 4, c = lane & 15;
  const int wm = wave >> 1, wn = wave & 1;

  __shared__ unsigned short As[128][32];
  __shared__ unsigned short Bs[128][32];

  f32x4 acc[4][4];
#pragma unroll
  for (int i = 0; i < 4; ++i)
#pragma unroll
    for (int t = 0; t < 4; ++t) acc[i][t] = (f32x4){0.f, 0.f, 0.f, 0.f};

  const int ar = tid >> 1;
  const int ak = (tid & 1) * 16;
  const int bk = tid >> 3;
  const int bn0 = (tid & 7) * 16;

  for (int k0 = 0; k0 < NODE_DIM; k0 += 32) {
    {
      const int r = row0 + ar;
      short8 t0, t1;
      if (r < N_NODES) {
        const float4* src = (const float4*)&x[(size_t)r * NODE_DIM + k0 + ak];
        float4 f0 = src[0], f1 = src[1], f2 = src[2], f3 = src[3];
        t0[0]=f2bf(f0.x); t0[1]=f2bf(f0.y); t0[2]=f2bf(f0.z); t0[3]=f2bf(f0.w);
        t0[4]=f2bf(f1.x); t0[5]=f2bf(f1.y); t0[6]=f2bf(f1.z); t0[7]=f2bf(f1.w);
        t1[0]=f2bf(f2.x); t1[1]=f2bf(f2.y); t1[2]=f2bf(f2.z); t1[3]=f2bf(f2.w);
        t1[4]=f2bf(f3.x); t1[5]=f2bf(f3.y); t1[6]=f2bf(f3.z); t1[7]=f2bf(f3.w);
      } else {
#pragma unroll
        for (int j = 0; j < 8; ++j) { t0[j] = 0; t1[j] = 0; }
      }
      *(short8*)&As[ar][ak] = t0;
      *(short8*)&As[ar][ak + 8] = t1;
    }
    {
      const float4* src = (const float4*)&We[(size_t)(half * 256 + k0 + bk) * HIDDEN + ncol0 + bn0];
#pragma unroll
      for (int v = 0; v < 4; ++v) {
        float4 f = src[v];
        Bs[bn0 + v * 4 + 0][bk] = f2bf(f.x);
        Bs[bn0 + v * 4 + 1][bk] = f2bf(f.y);
        Bs[bn0 + v * 4 + 2][bk] = f2bf(f.z);
        Bs[bn0 + v * 4 + 3][bk] = f2bf(f.w);
      }
    }
    __syncthreads();
    short8 Af[4], Bf[4];
#pragma unroll
    for (int i = 0; i < 4; ++i) Af[i] = *(const short8*)&As[wm * 64 + i * 16 + c][q * 8];
#pragma unroll
    for (int t = 0; t < 4; ++t) Bf[t] = *(const short8*)&Bs[wn * 64 + t * 16 + c][q * 8];
#pragma unroll
    for (int i = 0; i < 4; ++i)
#pragma unroll
      for (int t = 0; t < 4; ++t)
        acc[i][t] = __builtin_amdgcn_mfma_f32_16x16x32_bf16(Af[i], Bf[t], acc[i][t], 0, 0, 0);
    __syncthreads();
  }

  float biasv[4] = {0.f, 0.f, 0.f, 0.f};
  const int nbase = ncol0 + wn * 64;
  if (half) {
#pragma unroll
    for (int t = 0; t < 4; ++t) biasv[t] = be[nbase + t * 16 + c];
  }
#pragma unroll
  for (int i = 0; i < 4; ++i) {
#pragma unroll
    for (int r = 0; r < 4; ++r) {
      const int node = row0 + wm * 64 + i * 16 + q * 4 + r;
      if (node < N_NODES) {
        ushort4 o;
        o.x = f2bf(acc[i][0][r] + biasv[0]);
        o.y = f2bf(acc[i][1][r] + biasv[1]);
        o.z = f2bf(acc[i][2][r] + biasv[2]);
        o.w = f2bf(acc[i][3][r] + biasv[3]);
        *(ushort4*)&C[(size_t)node * 512 + half * 256 + nbase + c * 4] = o;
      }
    }
  }
}

// ---------------- Kernel 2: MFMA fused gather + attr-GEMM + relu + mean.
// EXACT round-0 structure (96.9 us): zero-C MFMA overlaps with gathers;
// base added on VALU after gathers land.
template <bool PRE>
__global__ __launch_bounds__(256) void edge_mfma(
    const unsigned short* __restrict__ C, const int* __restrict__ ei,
    const float* __restrict__ attrs_f, const unsigned short* __restrict__ attrs_b,
    const float* __restrict__ We, float* __restrict__ partial) {
  const int tid = threadIdx.x;
  const int lane = tid & 63, wave = tid >> 6;
  const int q = lane >> 4, c = lane & 15;
  const int hb = wave * 64;

  short8 Bf[4];
#pragma unroll
  for (int t = 0; t < 4; ++t) {
    short8 bf;
#pragma unroll
    for (int j = 0; j < 8; ++j) {
      int k = q * 8 + j;
      float w = (k < 16) ? We[(size_t)(512 + k) * HIDDEN + hb + t * 16 + c] : 0.0f;
      bf[j] = (short)f2bf(w);
    }
    Bf[t] = bf;
  }

  f32x4 acc4[4][4];  // [b][t]
#pragma unroll
  for (int b = 0; b < 4; ++b)
#pragma unroll
    for (int t = 0; t < 4; ++t) acc4[b][t] = (f32x4){0.f, 0.f, 0.f, 0.f};

  const f32x4 zero4 = {0.f, 0.f, 0.f, 0.f};
  const int ngroups = N_EDGES / 16;
  for (int g = blockIdx.x; g < ngroups; g += gridDim.x) {
    const int e0 = g * 16;
    const int4 ns4 = *(const int4*)&ei[e0 + q * 4];
    const int4 nd4 = *(const int4*)&ei[N_EDGES + e0 + q * 4];

    short8 Af[4];
    if (PRE) {
      if (q < 2) {
#pragma unroll
        for (int b = 0; b < 4; ++b)
          Af[b] = *(const short8*)&attrs_b[((size_t)b * N_EDGES + e0 + c) * 16 + q * 8];
      } else {
        short8 z;
#pragma unroll
        for (int j = 0; j < 8; ++j) z[j] = 0;
#pragma unroll
        for (int b = 0; b < 4; ++b) Af[b] = z;
      }
    } else {
      if (q < 2) {
#pragma unroll
        for (int b = 0; b < 4; ++b) {
          const size_t off = ((size_t)b * N_EDGES + e0 + c) * 16 + q * 8;
          const float4 a0 = *(const float4*)&attrs_f[off];
          const float4 a1 = *(const float4*)&attrs_f[off + 4];
          short8 af;
          af[0]=f2bf(a0.x); af[1]=f2bf(a0.y); af[2]=f2bf(a0.z); af[3]=f2bf(a0.w);
          af[4]=f2bf(a1.x); af[5]=f2bf(a1.y); af[6]=f2bf(a1.z); af[7]=f2bf(a1.w);
          Af[b] = af;
        }
      } else {
        short8 z;
#pragma unroll
        for (int j = 0; j < 8; ++j) z[j] = 0;
#pragma unroll
        for (int b = 0; b < 4; ++b) Af[b] = z;
      }
    }

    f32x4 base4[4];  // [t], component = row r (bias already folded into dst half)
    {
      const int nn[4] = {ns4.x, ns4.y, ns4.z, ns4.w};
      const int dd[4] = {nd4.x, nd4.y, nd4.z, nd4.w};
#pragma unroll
      for (int r = 0; r < 4; ++r) {
        const uint2 s = *(const uint2*)&C[(size_t)nn[r] * 512 + hb + c * 4];
        const uint2 d = *(const uint2*)&C[(size_t)dd[r] * 512 + 256 + hb + c * 4];
        base4[0][r] = __uint_as_float(s.x << 16) + __uint_as_float(d.x << 16);
        base4[1][r] = __uint_as_float(s.x & 0xFFFF0000u) + __uint_as_float(d.x & 0xFFFF0000u);
        base4[2][r] = __uint_as_float(s.y << 16) + __uint_as_float(d.y << 16);
        base4[3][r] = __uint_as_float(s.y & 0xFFFF0000u) + __uint_as_float(d.y & 0xFFFF0000u);
      }
    }

#pragma unroll
    for (int b = 0; b < 4; ++b) {
#pragma unroll
      for (int t = 0; t < 4; ++t) {
        f32x4 S = __builtin_amdgcn_mfma_f32_16x16x32_bf16(Af[b], Bf[t], zero4, 0, 0, 0);
        f32x4 u = S + base4[t];
        u[0] = fmaxf(u[0], 0.f); u[1] = fmaxf(u[1], 0.f);
        u[2] = fmaxf(u[2], 0.f); u[3] = fmaxf(u[3], 0.f);
        acc4[b][t] += u;
      }
    }
  }

#pragma unroll
  for (int b = 0; b < 4; ++b)
#pragma unroll
    for (int t = 0; t < 4; ++t) {
      float v = acc4[b][t][0] + acc4[b][t][1] + acc4[b][t][2] + acc4[b][t][3];
      v += __shfl_xor(v, 16, 64);
      v += __shfl_xor(v, 32, 64);
      if (q == 0) atomicAdd(&partial[b * HIDDEN + hb + t * 16 + c], v);
    }
}

// ---------------- Kernel 3: out[b,o] = (S[b,:]/E) @ W_graph + b_graph
__global__ __launch_bounds__(256) void graph_out(
    const float* __restrict__ partial, const float* __restrict__ Wg,
    const float* __restrict__ bg, float* __restrict__ out) {
  const int o = blockIdx.x;    // 0..127
  const int hh = threadIdx.x;  // 0..255
  const int lane = hh & 63, wave = hh >> 6;
  const float w = Wg[(size_t)hh * OUT_DIM + o];
  float v[4];
#pragma unroll
  for (int b = 0; b < 4; ++b) v[b] = partial[b * HIDDEN + hh] * w;
#pragma unroll
  for (int off = 32; off >= 1; off >>= 1)
#pragma unroll
    for (int b = 0; b < 4; ++b) v[b] += __shfl_down(v[b], off, 64);
  __shared__ float red[4][4];
  if (lane == 0)
#pragma unroll
    for (int b = 0; b < 4; ++b) red[wave][b] = v[b];
  __syncthreads();
  if (hh < 4) {
    float s = red[0][hh] + red[1][hh] + red[2][hh] + red[3][hh];
    out[hh * OUT_DIM + o] = s * (1.0f / (float)N_EDGES) + bg[o];
  }
}

extern "C" void kernel_launch(void* const* d_in, const int* in_sizes, int n_in,
                              void* d_out, int out_size, void* d_ws, size_t ws_size,
                              hipStream_t stream) {
  const float* x  = (const float*)d_in[0];
  const int*   ei = (const int*)d_in[1];
  const float* ea = (const float*)d_in[2];
  const float* We = (const float*)d_in[3];
  const float* be = (const float*)d_in[4];
  const float* Wg = (const float*)d_in[5];
  const float* bg = (const float*)d_in[6];
  float* out = (float*)d_out;

  const size_t C_bytes = (size_t)N_NODES * 512 * 2;          // 20.48 MB
  const size_t A_bytes = (size_t)4 * N_EDGES * 16 * 2;       // 51.2 MB
  const size_t X_bytes = (size_t)N_NODES * NODE_DIM * 2;     // 10.24 MB
  const size_t W_bytes = (size_t)2 * 256 * 256 * 2;          // 256 KB
  unsigned short* C = (unsigned short*)d_ws;

  const bool tier2 = ws_size >= C_bytes + A_bytes + X_bytes + W_bytes + 4096;
  const bool tier1 = ws_size >= C_bytes + A_bytes + 4096;

  if (tier2) {
    unsigned short* attrs_bf = (unsigned short*)((char*)d_ws + C_bytes);
    unsigned short* xb = (unsigned short*)((char*)d_ws + C_bytes + A_bytes);
    unsigned short* Wt = (unsigned short*)((char*)d_ws + C_bytes + A_bytes + X_bytes);
    float* partial = (float*)((char*)d_ws + C_bytes + A_bytes + X_bytes + W_bytes);
    prep<<<2048, 256, 0, stream>>>(x, We, ea, xb, Wt, attrs_bf, partial);
    proj_bf<<<PROJ_BLOCKS, 256, 0, stream>>>(xb, Wt, be, C);
    edge_mfma<true><<<2048, 256, 0, stream>>>(C, ei, nullptr, attrs_bf, We, partial);
    graph_out<<<128, 256, 0, stream>>>(partial, Wg, bg, out);
  } else if (tier1) {
    unsigned short* attrs_bf = (unsigned short*)((char*)d_ws + C_bytes);
    float* partial = (float*)((char*)d_ws + C_bytes + A_bytes);
    proj_mfma<<<PROJ_BLOCKS + CONV_BLOCKS, 256, 0, stream>>>(x, We, be, C, partial, ea, attrs_bf);
    edge_mfma<true><<<2048, 256, 0, stream>>>(C, ei, nullptr, attrs_bf, We, partial);
    graph_out<<<128, 256, 0, stream>>>(partial, Wg, bg, out);
  } else {
    float* partial = (float*)((char*)d_ws + C_bytes);
    proj_mfma<<<PROJ_BLOCKS, 256, 0, stream>>>(x, We, be, C, partial, ea, nullptr);
    edge_mfma<false><<<2048, 256, 0, stream>>>(C, ei, ea, nullptr, We, partial);
    graph_out<<<128, 256, 0, stream>>>(partial, Wg, bg, out);
  }
}

// Round 5
// 279.967 us; speedup vs baseline: 1.5635x; 1.0257x over previous
//
#include <hip/hip_runtime.h>

#define N_NODES 20000
#define N_EDGES 400000
#define NODE_DIM 256
#define HIDDEN 256
#define OUT_DIM 128
#define PROJ_BLOCKS 628   // 157 m-blocks * 4 n-blocks
#define CONV_BLOCKS 1024  // rebalanced: conv is the long pole of the fused dispatch
#define EDGE_GRID 1250    // 25000 groups / 1250 = exactly 20 per block (no tail)

typedef __attribute__((ext_vector_type(8))) short short8;
typedef __attribute__((ext_vector_type(4))) float f32x4;

__device__ inline unsigned short f2bf(float f) {
  union { float f; unsigned u; } v; v.f = f;
  unsigned r = (v.u + 0x7FFFu + ((v.u >> 16) & 1u)) >> 16;
  return (unsigned short)r;
}

// ---------------- Kernel 1: bf16 MFMA proj GEMM + attrs->bf16 convert.
// C layout (bf16): C[node][half*256 + n64blk + c*4 + t] where h = n64blk + t*16 + c.
// half 0 = x@W_src, half 1 = x@W_dst + b_edge (bias folded here).
__global__ __launch_bounds__(256) void proj_mfma(
    const float* __restrict__ x, const float* __restrict__ We,
    const float* __restrict__ be, unsigned short* __restrict__ C,
    float* __restrict__ partial, const float* __restrict__ attrs,
    unsigned short* __restrict__ attrs_bf) {
  const int tid = threadIdx.x;
  if (blockIdx.x >= PROJ_BLOCKS) {
    // convert attrs fp32 -> bf16 (only launched when ws has room)
    const int nt = CONV_BLOCKS * 256;
    const int total4 = 4 * N_EDGES * 16 / 4;
    for (int i = (blockIdx.x - PROJ_BLOCKS) * 256 + tid; i < total4; i += nt) {
      float4 v = ((const float4*)attrs)[i];
      ushort4 o;
      o.x = f2bf(v.x); o.y = f2bf(v.y); o.z = f2bf(v.z); o.w = f2bf(v.w);
      ((ushort4*)attrs_bf)[i] = o;
    }
    return;
  }
  if (blockIdx.x == 0) {
    for (int i = tid; i < 4 * HIDDEN; i += 256) partial[i] = 0.f;
  }
  const int bm = blockIdx.x >> 2;
  const int bn = blockIdx.x & 3;
  const int row0 = bm * 128;
  const int col0 = bn * 128;          // 0,128,256,384
  const int half = col0 >> 8;         // 0: W_src, 1: W_dst
  const int ncol0 = col0 & 255;       // 0 or 128 within half
  const int lane = tid & 63, wave = tid >> 6;
  const int q = lane >> 4, c = lane & 15;
  const int wm = wave >> 1, wn = wave & 1;

  __shared__ unsigned short As[128][32];  // [m][k]
  __shared__ unsigned short Bs[128][32];  // [n][k] (transposed W)

  f32x4 acc[4][4];
#pragma unroll
  for (int i = 0; i < 4; ++i)
#pragma unroll
    for (int t = 0; t < 4; ++t) acc[i][t] = (f32x4){0.f, 0.f, 0.f, 0.f};

  const int ar = tid >> 1;            // A stage row 0..127
  const int ak = (tid & 1) * 16;      // A stage k 0/16
  const int bk = tid >> 3;            // B stage k 0..31
  const int bn0 = (tid & 7) * 16;     // B stage n 0..112

  for (int k0 = 0; k0 < NODE_DIM; k0 += 32) {
    {  // A: x rows -> bf16 LDS
      const int r = row0 + ar;
      short8 t0, t1;
      if (r < N_NODES) {
        const float4* src = (const float4*)&x[(size_t)r * NODE_DIM + k0 + ak];
        float4 f0 = src[0], f1 = src[1], f2 = src[2], f3 = src[3];
        t0[0]=f2bf(f0.x); t0[1]=f2bf(f0.y); t0[2]=f2bf(f0.z); t0[3]=f2bf(f0.w);
        t0[4]=f2bf(f1.x); t0[5]=f2bf(f1.y); t0[6]=f2bf(f1.z); t0[7]=f2bf(f1.w);
        t1[0]=f2bf(f2.x); t1[1]=f2bf(f2.y); t1[2]=f2bf(f2.z); t1[3]=f2bf(f2.w);
        t1[4]=f2bf(f3.x); t1[5]=f2bf(f3.y); t1[6]=f2bf(f3.z); t1[7]=f2bf(f3.w);
      } else {
#pragma unroll
        for (int j = 0; j < 8; ++j) { t0[j] = 0; t1[j] = 0; }
      }
      *(short8*)&As[ar][ak] = t0;
      *(short8*)&As[ar][ak + 8] = t1;
    }
    {  // B: We rows -> transposed bf16 LDS
      const float4* src = (const float4*)&We[(size_t)(half * 256 + k0 + bk) * HIDDEN + ncol0 + bn0];
#pragma unroll
      for (int v = 0; v < 4; ++v) {
        float4 f = src[v];
        Bs[bn0 + v * 4 + 0][bk] = f2bf(f.x);
        Bs[bn0 + v * 4 + 1][bk] = f2bf(f.y);
        Bs[bn0 + v * 4 + 2][bk] = f2bf(f.z);
        Bs[bn0 + v * 4 + 3][bk] = f2bf(f.w);
      }
    }
    __syncthreads();
    short8 Af[4], Bf[4];
#pragma unroll
    for (int i = 0; i < 4; ++i) Af[i] = *(const short8*)&As[wm * 64 + i * 16 + c][q * 8];
#pragma unroll
    for (int t = 0; t < 4; ++t) Bf[t] = *(const short8*)&Bs[wn * 64 + t * 16 + c][q * 8];
#pragma unroll
    for (int i = 0; i < 4; ++i)
#pragma unroll
      for (int t = 0; t < 4; ++t)
        acc[i][t] = __builtin_amdgcn_mfma_f32_16x16x32_bf16(Af[i], Bf[t], acc[i][t], 0, 0, 0);
    __syncthreads();
  }

  float biasv[4] = {0.f, 0.f, 0.f, 0.f};
  const int nbase = ncol0 + wn * 64;
  if (half) {
#pragma unroll
    for (int t = 0; t < 4; ++t) biasv[t] = be[nbase + t * 16 + c];
  }
#pragma unroll
  for (int i = 0; i < 4; ++i) {
#pragma unroll
    for (int r = 0; r < 4; ++r) {
      const int node = row0 + wm * 64 + i * 16 + q * 4 + r;
      if (node < N_NODES) {
        ushort4 o;
        o.x = f2bf(acc[i][0][r] + biasv[0]);
        o.y = f2bf(acc[i][1][r] + biasv[1]);
        o.z = f2bf(acc[i][2][r] + biasv[2]);
        o.w = f2bf(acc[i][3][r] + biasv[3]);
        *(ushort4*)&C[(size_t)node * 512 + half * 256 + nbase + c * 4] = o;
      }
    }
  }
}

// ---------------- Kernel 2: MFMA fused gather + attr-GEMM + relu + mean.
// EXACT round-0 structure (96.9 us): zero-C MFMA overlaps with gathers;
// base added on VALU after gathers land. Only change: uniform grid (1250
// blocks x 20 groups, no tail imbalance).
template <bool PRE>
__global__ __launch_bounds__(256) void edge_mfma(
    const unsigned short* __restrict__ C, const int* __restrict__ ei,
    const float* __restrict__ attrs_f, const unsigned short* __restrict__ attrs_b,
    const float* __restrict__ We, float* __restrict__ partial) {
  const int tid = threadIdx.x;
  const int lane = tid & 63, wave = tid >> 6;
  const int q = lane >> 4, c = lane & 15;
  const int hb = wave * 64;

  short8 Bf[4];
#pragma unroll
  for (int t = 0; t < 4; ++t) {
    short8 bf;
#pragma unroll
    for (int j = 0; j < 8; ++j) {
      int k = q * 8 + j;
      float w = (k < 16) ? We[(size_t)(512 + k) * HIDDEN + hb + t * 16 + c] : 0.0f;
      bf[j] = (short)f2bf(w);
    }
    Bf[t] = bf;
  }

  f32x4 acc4[4][4];  // [b][t]
#pragma unroll
  for (int b = 0; b < 4; ++b)
#pragma unroll
    for (int t = 0; t < 4; ++t) acc4[b][t] = (f32x4){0.f, 0.f, 0.f, 0.f};

  const f32x4 zero4 = {0.f, 0.f, 0.f, 0.f};
  const int ngroups = N_EDGES / 16;
  for (int g = blockIdx.x; g < ngroups; g += gridDim.x) {
    const int e0 = g * 16;
    const int4 ns4 = *(const int4*)&ei[e0 + q * 4];
    const int4 nd4 = *(const int4*)&ei[N_EDGES + e0 + q * 4];

    short8 Af[4];
    if (PRE) {
      if (q < 2) {
#pragma unroll
        for (int b = 0; b < 4; ++b)
          Af[b] = *(const short8*)&attrs_b[((size_t)b * N_EDGES + e0 + c) * 16 + q * 8];
      } else {
        short8 z;
#pragma unroll
        for (int j = 0; j < 8; ++j) z[j] = 0;
#pragma unroll
        for (int b = 0; b < 4; ++b) Af[b] = z;
      }
    } else {
      if (q < 2) {
#pragma unroll
        for (int b = 0; b < 4; ++b) {
          const size_t off = ((size_t)b * N_EDGES + e0 + c) * 16 + q * 8;
          const float4 a0 = *(const float4*)&attrs_f[off];
          const float4 a1 = *(const float4*)&attrs_f[off + 4];
          short8 af;
          af[0]=f2bf(a0.x); af[1]=f2bf(a0.y); af[2]=f2bf(a0.z); af[3]=f2bf(a0.w);
          af[4]=f2bf(a1.x); af[5]=f2bf(a1.y); af[6]=f2bf(a1.z); af[7]=f2bf(a1.w);
          Af[b] = af;
        }
      } else {
        short8 z;
#pragma unroll
        for (int j = 0; j < 8; ++j) z[j] = 0;
#pragma unroll
        for (int b = 0; b < 4; ++b) Af[b] = z;
      }
    }

    f32x4 base4[4];  // [t], component = row r (bias already folded into dst half)
    {
      const int nn[4] = {ns4.x, ns4.y, ns4.z, ns4.w};
      const int dd[4] = {nd4.x, nd4.y, nd4.z, nd4.w};
#pragma unroll
      for (int r = 0; r < 4; ++r) {
        const uint2 s = *(const uint2*)&C[(size_t)nn[r] * 512 + hb + c * 4];
        const uint2 d = *(const uint2*)&C[(size_t)dd[r] * 512 + 256 + hb + c * 4];
        base4[0][r] = __uint_as_float(s.x << 16) + __uint_as_float(d.x << 16);
        base4[1][r] = __uint_as_float(s.x & 0xFFFF0000u) + __uint_as_float(d.x & 0xFFFF0000u);
        base4[2][r] = __uint_as_float(s.y << 16) + __uint_as_float(d.y << 16);
        base4[3][r] = __uint_as_float(s.y & 0xFFFF0000u) + __uint_as_float(d.y & 0xFFFF0000u);
      }
    }

#pragma unroll
    for (int b = 0; b < 4; ++b) {
#pragma unroll
      for (int t = 0; t < 4; ++t) {
        f32x4 S = __builtin_amdgcn_mfma_f32_16x16x32_bf16(Af[b], Bf[t], zero4, 0, 0, 0);
        f32x4 u = S + base4[t];
        u[0] = fmaxf(u[0], 0.f); u[1] = fmaxf(u[1], 0.f);
        u[2] = fmaxf(u[2], 0.f); u[3] = fmaxf(u[3], 0.f);
        acc4[b][t] += u;
      }
    }
  }

#pragma unroll
  for (int b = 0; b < 4; ++b)
#pragma unroll
    for (int t = 0; t < 4; ++t) {
      float v = acc4[b][t][0] + acc4[b][t][1] + acc4[b][t][2] + acc4[b][t][3];
      v += __shfl_xor(v, 16, 64);
      v += __shfl_xor(v, 32, 64);
      if (q == 0) atomicAdd(&partial[b * HIDDEN + hb + t * 16 + c], v);
    }
}

// ---------------- Kernel 3: out[b,o] = (S[b,:]/E) @ W_graph + b_graph
__global__ __launch_bounds__(256) void graph_out(
    const float* __restrict__ partial, const float* __restrict__ Wg,
    const float* __restrict__ bg, float* __restrict__ out) {
  const int o = blockIdx.x;    // 0..127
  const int hh = threadIdx.x;  // 0..255
  const int lane = hh & 63, wave = hh >> 6;
  const float w = Wg[(size_t)hh * OUT_DIM + o];
  float v[4];
#pragma unroll
  for (int b = 0; b < 4; ++b) v[b] = partial[b * HIDDEN + hh] * w;
#pragma unroll
  for (int off = 32; off >= 1; off >>= 1)
#pragma unroll
    for (int b = 0; b < 4; ++b) v[b] += __shfl_down(v[b], off, 64);
  __shared__ float red[4][4];
  if (lane == 0)
#pragma unroll
    for (int b = 0; b < 4; ++b) red[wave][b] = v[b];
  __syncthreads();
  if (hh < 4) {
    float s = red[0][hh] + red[1][hh] + red[2][hh] + red[3][hh];
    out[hh * OUT_DIM + o] = s * (1.0f / (float)N_EDGES) + bg[o];
  }
}

extern "C" void kernel_launch(void* const* d_in, const int* in_sizes, int n_in,
                              void* d_out, int out_size, void* d_ws, size_t ws_size,
                              hipStream_t stream) {
  const float* x  = (const float*)d_in[0];
  const int*   ei = (const int*)d_in[1];
  const float* ea = (const float*)d_in[2];
  const float* We = (const float*)d_in[3];
  const float* be = (const float*)d_in[4];
  const float* Wg = (const float*)d_in[5];
  const float* bg = (const float*)d_in[6];
  float* out = (float*)d_out;

  const size_t C_bytes = (size_t)N_NODES * 512 * 2;         // 20.48 MB
  const size_t A_bytes = (size_t)4 * N_EDGES * 16 * 2;      // 51.2 MB
  unsigned short* C = (unsigned short*)d_ws;
  const bool pre = ws_size >= C_bytes + A_bytes + 4096;     // 76.23 MB (known-satisfied)
  unsigned short* attrs_bf = pre ? (unsigned short*)((char*)d_ws + C_bytes) : nullptr;
  float* partial = (float*)((char*)d_ws + (pre ? C_bytes + A_bytes : C_bytes));

  const int grid1 = pre ? PROJ_BLOCKS + CONV_BLOCKS : PROJ_BLOCKS;
  proj_mfma<<<grid1, 256, 0, stream>>>(x, We, be, C, partial, ea, attrs_bf);
  if (pre)
    edge_mfma<true><<<EDGE_GRID, 256, 0, stream>>>(C, ei, nullptr, attrs_bf, We, partial);
  else
    edge_mfma<false><<<EDGE_GRID, 256, 0, stream>>>(C, ei, ea, nullptr, We, partial);
  graph_out<<<128, 256, 0, stream>>>(partial, Wg, bg, out);
}